// Round 1
// baseline (673.854 us; speedup 1.0000x reference)
//
#include <hip/hip_runtime.h>

#define NSAMP 1024
#define NC 21
#define NFG 20
#define HW 1681
#define MIN_PROB 1e-4f
#define INV_NORM (1.0f/1.0021f)   // 1 / (1 + 21*MIN_PROB)

// log-scale histogram: bin = (float_bits >> 15) - BIN_BASE
// p in [1e-4/1.0021, ~0.998] -> exponent field 113..126 -> 14*256 = 3584 bins
#define NB 3584
#define BPT 14                    // bins per thread (256 threads)
#define BIN_BASE 28928            // 113 << 8
#define L2Q_FG (-0.0057823528f)   // log2(0.996)
#define L2Q_BG (-0.0014434217f)   // log2(0.999)

__device__ __forceinline__ float waveSum(float v) {
    #pragma unroll
    for (int o = 32; o > 0; o >>= 1) v += __shfl_down(v, o);
    return v;
}
__device__ __forceinline__ float waveMax(float v) {
    #pragma unroll
    for (int o = 32; o > 0; o >>= 1) v = fmaxf(v, __shfl_down(v, o));
    return v;
}

// Kernel A: per-pixel softmax; accumulates loss_s numerator/count per sample and
// global crf (loss_c) sum; writes logZ per pixel for kernel B.
__global__ __launch_bounds__(256) void kernelA(
    const float* __restrict__ outp, const float* __restrict__ gt,
    const float* __restrict__ crf, float* __restrict__ logZ,
    float* __restrict__ samp_s, float* __restrict__ samp_cnt,
    float* __restrict__ crf_acc)
{
    const int n = blockIdx.y;
    const int pix = blockIdx.x * 256 + threadIdx.x;
    const bool act = (pix < HW);
    const size_t base = (size_t)n * NC * HW;

    float t[NC];
    float a_s = 0.f, a_cnt = 0.f, a_c = 0.f;
    if (act) {
        float m = -3.0e38f;
        #pragma unroll
        for (int c = 0; c < NC; ++c) {
            t[c] = outp[base + (size_t)c * HW + pix];
            m = fmaxf(m, t[c]);
        }
        float S = 0.f;
        #pragma unroll
        for (int c = 0; c < NC; ++c) { t[c] = __expf(t[c] - m); S += t[c]; }
        const float invS = 1.0f / S;
        #pragma unroll
        for (int c = 0; c < NC; ++c) {
            float p  = (t[c] * invS + MIN_PROB) * INV_NORM;
            float lp = __logf(p);
            float g  = gt[base + (size_t)c * HW + pix];
            a_s  += g * lp;
            a_cnt += g;
            float cl = crf[base + (size_t)c * HW + pix];
            a_c += __expf(cl) * (cl - lp);
        }
        logZ[(size_t)n * HW + pix] = m + __logf(S);
    }
    a_s = waveSum(a_s); a_cnt = waveSum(a_cnt); a_c = waveSum(a_c);
    __shared__ float sred[3][4];
    const int lane = threadIdx.x & 63, wid = threadIdx.x >> 6;
    if (lane == 0) { sred[0][wid] = a_s; sred[1][wid] = a_cnt; sred[2][wid] = a_c; }
    __syncthreads();
    if (threadIdx.x == 0) {
        atomicAdd(&samp_s[n],   sred[0][0] + sred[0][1] + sred[0][2] + sred[0][3]);
        atomicAdd(&samp_cnt[n], sred[1][0] + sred[1][1] + sred[1][2] + sred[1][3]);
        atomicAdd(crf_acc,      sred[2][0] + sred[2][1] + sred[2][2] + sred[2][3]);
    }
}

// Kernel B: one block per (n, c). Counting-sort GWRP: log-scale histogram of the
// 1681 probs, suffix scan over bins (descending value) for rank offsets G, then
// exact geometric partial weight q^G (1 - q^cnt) / cnt per bin. Also max-reduce.
__global__ __launch_bounds__(256) void kernelB(
    const float* __restrict__ outp, const float* __restrict__ logZ,
    float* __restrict__ pm, float* __restrict__ pmx, float* __restrict__ pbg)
{
    __shared__ int   s_cnt[NB];
    __shared__ float s_vsum[NB];
    __shared__ int   s_scan[256];
    __shared__ float s_red[8];

    const int tid = threadIdx.x;
    const int n = blockIdx.x / NC;
    const int c = blockIdx.x % NC;

    for (int j = tid; j < NB; j += 256) { s_cnt[j] = 0; s_vsum[j] = 0.f; }
    __syncthreads();

    const float* ob = outp + ((size_t)n * NC + c) * HW;
    const float* lz = logZ + (size_t)n * HW;
    float maxv = 0.f;
    for (int i = tid; i < HW; i += 256) {
        float p = (__expf(ob[i] - lz[i]) + MIN_PROB) * INV_NORM;
        maxv = fmaxf(maxv, p);
        int b = (int)(__float_as_uint(p) >> 15) - BIN_BASE;
        b = min(max(b, 0), NB - 1);
        atomicAdd(&s_cnt[b], 1);
        atomicAdd(&s_vsum[b], p);
    }
    __syncthreads();

    // thread t owns bins [NB-1 - t*BPT .. NB - (t+1)*BPT] in descending order
    int cl = 0;
    #pragma unroll
    for (int j = 0; j < BPT; ++j) cl += s_cnt[NB - 1 - tid * BPT - j];
    s_scan[tid] = cl;
    __syncthreads();
    #pragma unroll
    for (int off = 1; off < 256; off <<= 1) {
        int v = s_scan[tid];
        int u = (tid >= off) ? s_scan[tid - off] : 0;
        __syncthreads();
        s_scan[tid] = v + u;
        __syncthreads();
    }
    int G = s_scan[tid] - cl;   // # elements in strictly higher bins

    const float l2q = (c == 0) ? L2Q_BG : L2Q_FG;
    float contrib = 0.f;
    #pragma unroll
    for (int j = 0; j < BPT; ++j) {
        int b  = NB - 1 - tid * BPT - j;
        int cb = s_cnt[b];
        if (cb > 0) {
            float qg = exp2f(l2q * (float)G);
            contrib += s_vsum[b] * qg * (1.0f - exp2f(l2q * (float)cb)) / (float)cb;
            G += cb;
        }
    }
    contrib = waveSum(contrib);
    maxv = waveMax(maxv);
    const int lane = tid & 63, wid = tid >> 6;
    if (lane == 0) { s_red[wid] = contrib; s_red[4 + wid] = maxv; }
    __syncthreads();
    if (tid == 0) {
        float total = s_red[0] + s_red[1] + s_red[2] + s_red[3];
        float mx = fmaxf(fmaxf(s_red[4], s_red[5]), fmaxf(s_red[6], s_red[7]));
        float denom = 1.0f - exp2f(l2q * (float)HW);   // normalizer sum(w) * (1-q)
        float mean = total / denom;
        if (c == 0) pbg[n] = mean;
        else { pm[(size_t)n * NFG + (c - 1)] = mean; pmx[(size_t)n * NFG + (c - 1)] = mx; }
    }
}

// Kernel C: final assembly over 1024 samples -> scalar loss.
__global__ __launch_bounds__(256) void kernelC(
    const float* __restrict__ label, const float* __restrict__ samp_s,
    const float* __restrict__ samp_cnt, const float* __restrict__ pm,
    const float* __restrict__ pmx, const float* __restrict__ pbg,
    const float* __restrict__ crf_acc, float* __restrict__ out)
{
    const int tid = threadIdx.x;
    float acc = 0.f;
    for (int n = tid; n < NSAMP; n += 256) {
        float v = samp_s[n] / samp_cnt[n];
        float s_stat = 0.f, l1 = 0.f, l2 = 0.f;
        #pragma unroll
        for (int c = 0; c < NFG; ++c) {
            float st = (label[(size_t)n * NC + 1 + c] > 0.5f) ? 1.0f : 0.0f;
            s_stat += st;
            l1 += st * __logf(pm[(size_t)n * NFG + c]);
            l2 += (1.0f - st) * __logf(1.0f - pmx[(size_t)n * NFG + c]);
        }
        acc += v + l1 / s_stat + l2 / ((float)NFG - s_stat) + __logf(pbg[n]);
    }
    acc = waveSum(acc);
    __shared__ float s_red[4];
    const int lane = tid & 63, wid = tid >> 6;
    if (lane == 0) s_red[wid] = acc;
    __syncthreads();
    if (tid == 0) {
        float tot = s_red[0] + s_red[1] + s_red[2] + s_red[3];
        out[0] = -(tot / (float)NSAMP) + crf_acc[0] / ((float)NSAMP * (float)HW);
    }
}

extern "C" void kernel_launch(void* const* d_in, const int* in_sizes, int n_in,
                              void* d_out, int out_size, void* d_ws, size_t ws_size,
                              hipStream_t stream)
{
    const float* outp  = (const float*)d_in[0];
    const float* gt    = (const float*)d_in[1];
    const float* label = (const float*)d_in[2];
    const float* crf   = (const float*)d_in[3];
    float* out = (float*)d_out;

    float* ws = (float*)d_ws;
    float* samp_s   = ws;                  // 1024
    float* samp_cnt = ws + 1024;           // 1024
    float* crf_acc  = ws + 2048;           // 1 (+pad to 2064)
    float* pm   = ws + 2064;               // 1024*20
    float* pmx  = pm + NSAMP * NFG;        // 1024*20
    float* pbg  = pmx + NSAMP * NFG;       // 1024
    float* logZ = pbg + NSAMP;             // 1024*1681  (~6.9 MB total ws use)

    hipMemsetAsync(d_ws, 0, 2064 * sizeof(float), stream);

    dim3 gridA((HW + 255) / 256, NSAMP);
    kernelA<<<gridA, 256, 0, stream>>>(outp, gt, crf, logZ, samp_s, samp_cnt, crf_acc);
    kernelB<<<NSAMP * NC, 256, 0, stream>>>(outp, logZ, pm, pmx, pbg);
    kernelC<<<1, 256, 0, stream>>>(label, samp_s, samp_cnt, pm, pmx, pbg, crf_acc, out);
}

// Round 2
// 493.394 us; speedup vs baseline: 1.3658x; 1.3658x over previous
//
#include <hip/hip_runtime.h>

#define NSAMP 1024
#define NC 21
#define NFG 20
#define HW 1681
#define MIN_PROB 1e-4f
#define INV_NORM (1.0f/1.0021f)   // 1 / (1 + 21*MIN_PROB)

// log-scale histogram for kernelB: bin = (float_bits >> 16) - BIN_BASE
// exponent(8 bits) + 7 mantissa bits -> 0.78% bin width.
// p in [9.98e-5, 0.998] -> exponent field 113..126; base at 111 gives margin.
#define NB 2048
#define BPT 8                     // bins per thread (256 threads)
#define BIN_BASE (111 << 7)       // 14208
#define L2Q_FG (-0.0057823528f)   // log2(0.996)
#define L2Q_BG (-0.0014434217f)   // log2(0.999)

__device__ __forceinline__ float waveSum(float v) {
    #pragma unroll
    for (int o = 32; o > 0; o >>= 1) v += __shfl_down(v, o);
    return v;
}
__device__ __forceinline__ float waveMax(float v) {
    #pragma unroll
    for (int o = 32; o > 0; o >>= 1) v = fmaxf(v, __shfl_down(v, o));
    return v;
}

// Kernel A (unchanged): per-pixel softmax; accumulates loss_s numerator/count
// per sample and global crf (loss_c) sum; writes logZ per pixel for kernel B.
__global__ __launch_bounds__(256) void kernelA(
    const float* __restrict__ outp, const float* __restrict__ gt,
    const float* __restrict__ crf, float* __restrict__ logZ,
    float* __restrict__ samp_s, float* __restrict__ samp_cnt,
    float* __restrict__ crf_acc)
{
    const int n = blockIdx.y;
    const int pix = blockIdx.x * 256 + threadIdx.x;
    const bool act = (pix < HW);
    const size_t base = (size_t)n * NC * HW;

    float t[NC];
    float a_s = 0.f, a_cnt = 0.f, a_c = 0.f;
    if (act) {
        float m = -3.0e38f;
        #pragma unroll
        for (int c = 0; c < NC; ++c) {
            t[c] = outp[base + (size_t)c * HW + pix];
            m = fmaxf(m, t[c]);
        }
        float S = 0.f;
        #pragma unroll
        for (int c = 0; c < NC; ++c) { t[c] = __expf(t[c] - m); S += t[c]; }
        const float invS = 1.0f / S;
        #pragma unroll
        for (int c = 0; c < NC; ++c) {
            float p  = (t[c] * invS + MIN_PROB) * INV_NORM;
            float lp = __logf(p);
            float g  = gt[base + (size_t)c * HW + pix];
            a_s  += g * lp;
            a_cnt += g;
            float cl = crf[base + (size_t)c * HW + pix];
            a_c += __expf(cl) * (cl - lp);
        }
        logZ[(size_t)n * HW + pix] = m + __logf(S);
    }
    a_s = waveSum(a_s); a_cnt = waveSum(a_cnt); a_c = waveSum(a_c);
    __shared__ float sred[3][4];
    const int lane = threadIdx.x & 63, wid = threadIdx.x >> 6;
    if (lane == 0) { sred[0][wid] = a_s; sred[1][wid] = a_cnt; sred[2][wid] = a_c; }
    __syncthreads();
    if (threadIdx.x == 0) {
        atomicAdd(&samp_s[n],   sred[0][0] + sred[0][1] + sred[0][2] + sred[0][3]);
        atomicAdd(&samp_cnt[n], sred[1][0] + sred[1][1] + sred[1][2] + sred[1][3]);
        atomicAdd(crf_acc,      sred[2][0] + sred[2][1] + sred[2][2] + sred[2][3]);
    }
}

// Kernel B v2: one block per (n, c). Counting-sort GWRP with:
//  - packed 64-bit histogram entry: count in bits [44..], value-sum as
//    2^-32 fixed point in bits [0..43] -> ONE LDS atomic per element
//  - 2048 bins (7 mantissa bits)
//  - barrier-free wave-shuffle suffix scan (3 __syncthreads total)
__global__ __launch_bounds__(256) void kernelB(
    const float* __restrict__ outp, const float* __restrict__ logZ,
    float* __restrict__ pm, float* __restrict__ pmx, float* __restrict__ pbg)
{
    __shared__ unsigned long long s_hist[NB];
    __shared__ int   s_wt[4];
    __shared__ float s_red[8];

    const int tid = threadIdx.x;
    const int n = blockIdx.x / NC;
    const int c = blockIdx.x % NC;
    const int lane = tid & 63, wid = tid >> 6;

    #pragma unroll
    for (int j = 0; j < BPT; ++j) s_hist[tid + j * 256] = 0ULL;
    __syncthreads();

    const float* ob = outp + ((size_t)n * NC + c) * HW;
    const float* lz = logZ + (size_t)n * HW;
    float maxv = 0.f;
    for (int i = tid; i < HW; i += 256) {
        float p = (__expf(ob[i] - lz[i]) + MIN_PROB) * INV_NORM;
        maxv = fmaxf(maxv, p);
        int b = (int)(__float_as_uint(p) >> 16) - BIN_BASE;
        b = min(max(b, 0), NB - 1);
        unsigned long long pk = (1ULL << 44) |
            (unsigned long long)(p * 4294967296.0f);
        atomicAdd(&s_hist[b], pk);
    }
    __syncthreads();

    // thread tid owns bins NB-1-tid*BPT-j (j=0..BPT-1), i.e. descending value
    // order with increasing tid. Read back, unpack.
    int   cnt[BPT];
    float vs[BPT];
    int cl = 0;
    #pragma unroll
    for (int j = 0; j < BPT; ++j) {
        unsigned long long pk = s_hist[NB - 1 - tid * BPT - j];
        cnt[j] = (int)(pk >> 44);
        vs[j]  = (float)(pk & 0xFFFFFFFFFFFULL) * (1.0f / 4294967296.0f);
        cl += cnt[j];
    }

    // exclusive prefix of cl in tid order = # elements in strictly higher bins
    int incl = cl;
    #pragma unroll
    for (int o = 1; o < 64; o <<= 1) {
        int u = __shfl_up(incl, o);
        if (lane >= o) incl += u;
    }
    if (lane == 63) s_wt[wid] = incl;   // wave total
    __syncthreads();
    int G = incl - cl;
    for (int w = 0; w < 4; ++w) if (w < wid) G += s_wt[w];

    const float l2q = (c == 0) ? L2Q_BG : L2Q_FG;
    float contrib = 0.f;
    #pragma unroll
    for (int j = 0; j < BPT; ++j) {
        int cb = cnt[j];
        if (cb > 0) {
            float qg = exp2f(l2q * (float)G);
            contrib += vs[j] * qg * (1.0f - exp2f(l2q * (float)cb)) / (float)cb;
            G += cb;
        }
    }
    contrib = waveSum(contrib);
    maxv = waveMax(maxv);
    if (lane == 0) { s_red[wid] = contrib; s_red[4 + wid] = maxv; }
    __syncthreads();
    if (tid == 0) {
        float total = s_red[0] + s_red[1] + s_red[2] + s_red[3];
        float mx = fmaxf(fmaxf(s_red[4], s_red[5]), fmaxf(s_red[6], s_red[7]));
        float denom = 1.0f - exp2f(l2q * (float)HW);   // sum(w) * (1-q)
        float mean = total / denom;
        if (c == 0) pbg[n] = mean;
        else { pm[(size_t)n * NFG + (c - 1)] = mean; pmx[(size_t)n * NFG + (c - 1)] = mx; }
    }
}

// Kernel C: final assembly over 1024 samples -> scalar loss.
__global__ __launch_bounds__(256) void kernelC(
    const float* __restrict__ label, const float* __restrict__ samp_s,
    const float* __restrict__ samp_cnt, const float* __restrict__ pm,
    const float* __restrict__ pmx, const float* __restrict__ pbg,
    const float* __restrict__ crf_acc, float* __restrict__ out)
{
    const int tid = threadIdx.x;
    float acc = 0.f;
    for (int n = tid; n < NSAMP; n += 256) {
        float v = samp_s[n] / samp_cnt[n];
        float s_stat = 0.f, l1 = 0.f, l2 = 0.f;
        #pragma unroll
        for (int c = 0; c < NFG; ++c) {
            float st = (label[(size_t)n * NC + 1 + c] > 0.5f) ? 1.0f : 0.0f;
            s_stat += st;
            l1 += st * __logf(pm[(size_t)n * NFG + c]);
            l2 += (1.0f - st) * __logf(1.0f - pmx[(size_t)n * NFG + c]);
        }
        acc += v + l1 / s_stat + l2 / ((float)NFG - s_stat) + __logf(pbg[n]);
    }
    acc = waveSum(acc);
    __shared__ float s_red[4];
    const int lane = tid & 63, wid = tid >> 6;
    if (lane == 0) s_red[wid] = acc;
    __syncthreads();
    if (tid == 0) {
        float tot = s_red[0] + s_red[1] + s_red[2] + s_red[3];
        out[0] = -(tot / (float)NSAMP) + crf_acc[0] / ((float)NSAMP * (float)HW);
    }
}

extern "C" void kernel_launch(void* const* d_in, const int* in_sizes, int n_in,
                              void* d_out, int out_size, void* d_ws, size_t ws_size,
                              hipStream_t stream)
{
    const float* outp  = (const float*)d_in[0];
    const float* gt    = (const float*)d_in[1];
    const float* label = (const float*)d_in[2];
    const float* crf   = (const float*)d_in[3];
    float* out = (float*)d_out;

    float* ws = (float*)d_ws;
    float* samp_s   = ws;                  // 1024
    float* samp_cnt = ws + 1024;           // 1024
    float* crf_acc  = ws + 2048;           // 1 (+pad to 2064)
    float* pm   = ws + 2064;               // 1024*20
    float* pmx  = pm + NSAMP * NFG;        // 1024*20
    float* pbg  = pmx + NSAMP * NFG;       // 1024
    float* logZ = pbg + NSAMP;             // 1024*1681  (~6.9 MB total ws use)

    hipMemsetAsync(d_ws, 0, 2064 * sizeof(float), stream);

    dim3 gridA((HW + 255) / 256, NSAMP);
    kernelA<<<gridA, 256, 0, stream>>>(outp, gt, crf, logZ, samp_s, samp_cnt, crf_acc);
    kernelB<<<NSAMP * NC, 256, 0, stream>>>(outp, logZ, pm, pmx, pbg);
    kernelC<<<1, 256, 0, stream>>>(label, samp_s, samp_cnt, pm, pmx, pbg, crf_acc, out);
}